// Round 3
// baseline (161.733 us; speedup 1.0000x reference)
//
#include <hip/hip_runtime.h>
#include <math.h>

#define BB 256
#define NN 1024
#define KK 64
#define EE 128
#define TM 64   // rows per block in main kernel

typedef _Float16 half8 __attribute__((ext_vector_type(8)));
typedef float f32x4 __attribute__((ext_vector_type(4)));

// swizzled half-index for a [rows][128] f16 LDS tile: XOR 16B-slot bits by row&7
__device__ __forceinline__ int swz(int row, int halfcol) {
    return (row * EE + halfcol) ^ ((row & 7) << 3);
}

// ---------------- prep: per-batch combined matrix Mt (f16), bias; + W2 -> f16 ----------------
// C = adj @ (w_real + i w_imag); M = [[Cr, Ci], [-Ci, Cr]]; x_pre = [cos|sin] @ M + [br|bi]
// Mt[f][j] = M[j][f]  (so MFMA B-frags are contiguous rows)
__global__ __launch_bounds__(256) void prep_kernel(
    const float* __restrict__ recip,      // B*9
    const int* __restrict__ space_group,  // B
    const float* __restrict__ graphs,     // NSG*K*K
    const float* __restrict__ w_real,     // NSG*K*K
    const float* __restrict__ w_imag,     // NSG*K*K
    const float* __restrict__ b_real,     // NSG*K
    const float* __restrict__ b_imag,     // NSG*K
    const float* __restrict__ W2,         // E*E
    _Float16* __restrict__ Mt,            // B*E*E
    float* __restrict__ bbout,            // B*E
    _Float16* __restrict__ W2h)           // E*E
{
    const int b = blockIdx.x;
    const int t = threadIdx.x;
    const int sg = space_group[b] - 1;

    // fold W2 f32->f16 conversion into the first 64 blocks
    if (b < EE * EE / 256) {
        const int idx = b * 256 + t;
        W2h[idx] = (_Float16)W2[idx];
    }

    __shared__ float adjL[KK * KK];
    __shared__ float wrL[KK * KK];
    __shared__ float wiL[KK * KK];

    const float* adjG = graphs + (size_t)sg * KK * KK;
    const float* wrG  = w_real + (size_t)sg * KK * KK;
    const float* wiG  = w_imag + (size_t)sg * KK * KK;
    for (int idx = t; idx < KK * KK; idx += 256) {
        adjL[idx] = adjG[idx];
        wrL[idx]  = wrG[idx];
        wiL[idx]  = wiG[idx];
    }
    __syncthreads();

    // thread: C-row i = t>>2, 16 C-cols starting at (t&3)*16
    const int i  = t >> 2;
    const int f0 = (t & 3) * 16;
    float cr[16], ci[16];
#pragma unroll
    for (int c = 0; c < 16; ++c) { cr[c] = 0.f; ci[c] = 0.f; }
    for (int k = 0; k < KK; ++k) {
        const float a = adjL[i * KK + k];
#pragma unroll
        for (int c = 0; c < 16; ++c) {
            cr[c] += a * wrL[k * KK + f0 + c];
            ci[c] += a * wiL[k * KK + f0 + c];
        }
    }
    _Float16* Mb = Mt + (size_t)b * EE * EE;
#pragma unroll
    for (int c = 0; c < 16; ++c) {
        const int f = f0 + c;
        Mb[f * EE + i]             = (_Float16)cr[c];
        Mb[f * EE + KK + i]        = (_Float16)(-ci[c]);
        Mb[(KK + f) * EE + i]      = (_Float16)ci[c];
        Mb[(KK + f) * EE + KK + i] = (_Float16)cr[c];
    }
    if (t < EE) {
        bbout[b * EE + t] = (t < KK) ? b_real[sg * KK + t] : b_imag[sg * KK + (t - KK)];
    }
}

// ---------------- main fused MFMA kernel ----------------
__global__ __launch_bounds__(256) void main_kernel(
    const float* __restrict__ pos,      // B*N*3
    const float* __restrict__ recip,    // B*9
    const float* __restrict__ abc,      // K*3
    const _Float16* __restrict__ Mt,    // B*E*E f16
    const float* __restrict__ bball,    // B*E
    const _Float16* __restrict__ W2h,   // E*E f16
    const float* __restrict__ b2,       // E
    const float* __restrict__ gamma,    // E
    const float* __restrict__ beta,     // E
    float* __restrict__ out)            // B*N*E
{
    const int blk = blockIdx.x;
    const int b  = blk >> 4;            // 16 blocks per batch
    const int n0 = (blk & 15) * TM;
    const int t  = threadIdx.x;
    const int w    = t >> 6;            // wave 0..3 -> rows w*16..w*16+15
    const int lane = t & 63;
    const int ln15 = lane & 15;
    const int kg   = lane >> 4;         // 0..3

    __shared__ float abcL[KK * 3];
    __shared__ __align__(16) _Float16 X[TM * EE];   // 16KB silu output

    if (t < KK * 3) abcL[t] = abc[t];
    __syncthreads();

    // ---- per-lane A-fragments via sincos (A layout: row=lane&15, k=(lane>>4)*8+j) ----
    const int grow = n0 + w * 16 + ln15;            // this lane's A row (global n)
    const float* pr = pos + ((size_t)b * NN + grow) * 3;
    const float px = pr[0], py = pr[1], pz = pr[2];
    const float* R = recip + b * 9;                 // uniform per block -> scalar loads
    const float u0 = px * R[0] + py * R[3] + pz * R[6];
    const float u1 = px * R[1] + py * R[4] + pz * R[7];
    const float u2 = px * R[2] + py * R[5] + pz * R[8];

    half8 afrag[4];
#pragma unroll
    for (int mq = 0; mq < 2; ++mq) {
        _Float16 cb[8], sb[8];
#pragma unroll
        for (int j = 0; j < 8; ++j) {
            const int k = mq * 32 + kg * 8 + j;
            const float ph = 6.28318530717958647692f *
                (u0 * abcL[k * 3 + 0] + u1 * abcL[k * 3 + 1] + u2 * abcL[k * 3 + 2]);
            float s, c;
            __sincosf(ph, &s, &c);
            cb[j] = (_Float16)c;
            sb[j] = (_Float16)s;
        }
        afrag[mq]     = *(half8*)cb;   // cos -> k-chunks 0,1
        afrag[mq + 2] = *(half8*)sb;   // sin -> k-chunks 2,3
    }

    // ---- matmul1: x_pre = A @ M  (B-frags direct from global/L2) ----
    const _Float16* Mb = Mt + (size_t)b * EE * EE;
    f32x4 acc[8];
#pragma unroll
    for (int nt = 0; nt < 8; ++nt) {
        const int n = nt * 16 + ln15;
        const half8* bp = (const half8*)(Mb + n * EE + kg * 8);
        f32x4 a = {0.f, 0.f, 0.f, 0.f};
#pragma unroll
        for (int kc = 0; kc < 4; ++kc) {
            a = __builtin_amdgcn_mfma_f32_16x16x32_f16(afrag[kc], bp[kc * 4], a, 0, 0, 0);
        }
        acc[nt] = a;
    }

    // ---- bias + silu -> X (f16, swizzled; D layout row=(lane>>4)*4+r2, col=lane&15) ----
#pragma unroll
    for (int nt = 0; nt < 8; ++nt) {
        const int col = nt * 16 + ln15;
        const float bbv = bball[b * EE + col];
#pragma unroll
        for (int r2 = 0; r2 < 4; ++r2) {
            const float v = acc[nt][r2] + bbv;
            const int rr = w * 16 + kg * 4 + r2;
            X[swz(rr, col)] = (_Float16)(v / (1.f + __expf(-v)));
        }
    }
    __syncthreads();

    // ---- matmul2: y = X @ W2^T (A from LDS, B-frags from global/L2) ----
    const int arow = w * 16 + ln15;
    half8 a2[4];
#pragma unroll
    for (int kc = 0; kc < 4; ++kc)
        a2[kc] = *(const half8*)&X[swz(arow, kc * 32 + kg * 8)];

    f32x4 acc2[8];
#pragma unroll
    for (int nt = 0; nt < 8; ++nt) {
        const int n = nt * 16 + ln15;
        const half8* wp = (const half8*)(W2h + n * EE + kg * 8);
        f32x4 a = {0.f, 0.f, 0.f, 0.f};
#pragma unroll
        for (int kc = 0; kc < 4; ++kc) {
            a = __builtin_amdgcn_mfma_f32_16x16x32_f16(a2[kc], wp[kc * 4], a, 0, 0, 0);
        }
        acc2[nt] = a;
    }

    // ---- + b2, LayerNorm over E (16-lane shfl), write out ----
    float y[8][4];
    float s[4] = {0.f, 0.f, 0.f, 0.f}, q[4] = {0.f, 0.f, 0.f, 0.f};
#pragma unroll
    for (int nt = 0; nt < 8; ++nt) {
        const int col = nt * 16 + ln15;
        const float b2v = b2[col];
#pragma unroll
        for (int r2 = 0; r2 < 4; ++r2) {
            const float v = acc2[nt][r2] + b2v;
            y[nt][r2] = v;
            s[r2] += v;
            q[r2] += v * v;
        }
    }
#pragma unroll
    for (int m = 1; m < 16; m <<= 1) {
#pragma unroll
        for (int r2 = 0; r2 < 4; ++r2) {
            s[r2] += __shfl_xor(s[r2], m);
            q[r2] += __shfl_xor(q[r2], m);
        }
    }
    const float inv = 1.f / EE;
#pragma unroll
    for (int nt = 0; nt < 8; ++nt) {
        const int col = nt * 16 + ln15;
        const float g  = gamma[col];
        const float be = beta[col];
#pragma unroll
        for (int r2 = 0; r2 < 4; ++r2) {
            const float mu = s[r2] * inv;
            const float rs = rsqrtf(fmaxf(q[r2] * inv - mu * mu, 0.f) + 1e-5f);
            const int rr = w * 16 + kg * 4 + r2;
            out[((size_t)b * NN + n0 + rr) * EE + col] = (y[nt][r2] - mu) * rs * g + be;
        }
    }
}

extern "C" void kernel_launch(void* const* d_in, const int* in_sizes, int n_in,
                              void* d_out, int out_size, void* d_ws, size_t ws_size,
                              hipStream_t stream) {
    const float* pos    = (const float*)d_in[0];
    const float* recip  = (const float*)d_in[1];
    const int*   sgp    = (const int*)d_in[2];
    const float* abc    = (const float*)d_in[3];
    const float* graphs = (const float*)d_in[4];
    const float* wr     = (const float*)d_in[5];
    const float* wi     = (const float*)d_in[6];
    const float* br     = (const float*)d_in[7];
    const float* bi     = (const float*)d_in[8];
    const float* W2     = (const float*)d_in[9];
    const float* b2     = (const float*)d_in[10];
    const float* gm     = (const float*)d_in[11];
    const float* bt     = (const float*)d_in[12];
    float* out = (float*)d_out;

    char* ws = (char*)d_ws;
    _Float16* Mt    = (_Float16*)ws;                                    // B*E*E f16 = 8 MiB
    _Float16* W2h   = (_Float16*)(ws + (size_t)BB * EE * EE * 2);       // E*E f16 = 32 KiB
    float*    bball = (float*)(ws + (size_t)BB * EE * EE * 2 + 32768);  // B*E f32

    hipLaunchKernelGGL(prep_kernel, dim3(BB), dim3(256), 0, stream,
                       recip, sgp, graphs, wr, wi, br, bi, W2, Mt, bball, W2h);
    hipLaunchKernelGGL(main_kernel, dim3(BB * NN / TM), dim3(256), 0, stream,
                       pos, recip, abc, Mt, bball, W2h, b2, gm, bt, out);
}

// Round 4
// 70.215 us; speedup vs baseline: 2.3034x; 2.3034x over previous
//
#include <hip/hip_runtime.h>
#include <math.h>

#define BB 256
#define NN 1024
#define KK 64
#define EE 128
#define TM 64   // rows per block in main kernel

typedef _Float16 half8 __attribute__((ext_vector_type(8)));
typedef float f32x4 __attribute__((ext_vector_type(4)));

// swizzled half-index for a [rows][128] f16 LDS tile: XOR 16B-slot bits by row&7
__device__ __forceinline__ int swz(int row, int halfcol) {
    return (row * EE + halfcol) ^ ((row & 7) << 3);
}

// async global->LDS 16B: linear LDS dest (base + lane*16), per-lane global src
__device__ __forceinline__ void gload_lds16(const void* g, void* l) {
    __builtin_amdgcn_global_load_lds(
        (const __attribute__((address_space(1))) unsigned int*)g,
        (__attribute__((address_space(3))) unsigned int*)l, 16, 0, 0);
}

// ---------------- prep: per-batch combined matrix Mt (f16), bias; + W2 -> f16 ----------------
// C = adj @ (w_real + i w_imag); M = [[Cr, Ci], [-Ci, Cr]]; x_pre = [cos|sin] @ M + [br|bi]
// Mt[f][j] = M[j][f]  (so MFMA B-frags are contiguous rows)
__global__ __launch_bounds__(256) void prep_kernel(
    const float* __restrict__ recip,      // B*9 (unused here, kept for signature stability)
    const int* __restrict__ space_group,  // B
    const float* __restrict__ graphs,     // NSG*K*K
    const float* __restrict__ w_real,     // NSG*K*K
    const float* __restrict__ w_imag,     // NSG*K*K
    const float* __restrict__ b_real,     // NSG*K
    const float* __restrict__ b_imag,     // NSG*K
    const float* __restrict__ W2,         // E*E
    _Float16* __restrict__ Mt,            // B*E*E
    float* __restrict__ bbout,            // B*E
    _Float16* __restrict__ W2h)           // E*E
{
    const int b = blockIdx.x;
    const int t = threadIdx.x;
    const int sg = space_group[b] - 1;

    // fold W2 f32->f16 conversion into the first 64 blocks
    if (b < EE * EE / 256) {
        const int idx = b * 256 + t;
        W2h[idx] = (_Float16)W2[idx];
    }

    __shared__ float adjL[KK * KK];
    __shared__ float wrL[KK * KK];
    __shared__ float wiL[KK * KK];

    const float* adjG = graphs + (size_t)sg * KK * KK;
    const float* wrG  = w_real + (size_t)sg * KK * KK;
    const float* wiG  = w_imag + (size_t)sg * KK * KK;
    for (int idx = t; idx < KK * KK; idx += 256) {
        adjL[idx] = adjG[idx];
        wrL[idx]  = wrG[idx];
        wiL[idx]  = wiG[idx];
    }
    __syncthreads();

    // thread: C-row i = t>>2, 16 C-cols starting at (t&3)*16
    const int i  = t >> 2;
    const int f0 = (t & 3) * 16;
    float cr[16], ci[16];
#pragma unroll
    for (int c = 0; c < 16; ++c) { cr[c] = 0.f; ci[c] = 0.f; }
    for (int k = 0; k < KK; ++k) {
        const float a = adjL[i * KK + k];
#pragma unroll
        for (int c = 0; c < 16; ++c) {
            cr[c] += a * wrL[k * KK + f0 + c];
            ci[c] += a * wiL[k * KK + f0 + c];
        }
    }
    _Float16* Mb = Mt + (size_t)b * EE * EE;
#pragma unroll
    for (int c = 0; c < 16; ++c) {
        const int f = f0 + c;
        Mb[f * EE + i]             = (_Float16)cr[c];
        Mb[f * EE + KK + i]        = (_Float16)(-ci[c]);
        Mb[(KK + f) * EE + i]      = (_Float16)ci[c];
        Mb[(KK + f) * EE + KK + i] = (_Float16)cr[c];
    }
    if (t < EE) {
        bbout[b * EE + t] = (t < KK) ? b_real[sg * KK + t] : b_imag[sg * KK + (t - KK)];
    }
}

// ---------------- main fused MFMA kernel ----------------
__global__ __launch_bounds__(256) void main_kernel(
    const float* __restrict__ pos,      // B*N*3
    const float* __restrict__ recip,    // B*9
    const float* __restrict__ abc,      // K*3
    const _Float16* __restrict__ Mt,    // B*E*E f16
    const float* __restrict__ bball,    // B*E
    const _Float16* __restrict__ W2h,   // E*E f16
    const float* __restrict__ b2,       // E
    const float* __restrict__ gamma,    // E
    const float* __restrict__ beta,     // E
    float* __restrict__ out)            // B*N*E
{
    const int d = blockIdx.x;
    // XCD swizzle: dispatch d -> XCD d&7. Put all 16 blocks of a batch on one XCD
    // so Mt's 32KB is fetched into that XCD's L2 once. 4096 wgs, 512 per XCD.
    const int j  = d >> 3;                  // 0..511 within XCD
    const int b  = (d & 7) * 32 + (j >> 4); // batch
    const int n0 = (j & 15) * TM;
    const int t  = threadIdx.x;
    const int w    = t >> 6;                // wave 0..3 -> rows w*16..w*16+15
    const int lane = t & 63;
    const int ln15 = lane & 15;
    const int kg   = lane >> 4;             // 0..3

    __shared__ __align__(16) _Float16 Bt[EE * EE];  // 32KB: Mt, later W2h
    __shared__ __align__(16) _Float16 X[TM * EE];   // 16KB: silu output
    __shared__ float abcL[KK * 3];

    if (t < KK * 3) abcL[t] = abc[t];
    __syncthreads();   // abcL visible (cheap; no big loads outstanding yet)

    // ---- issue async Mt staging: LDS linear, global source inverse-swizzled ----
    // LDS chunk c16=(row,slot) must hold global chunk (row, slot^(row&7)).
    {
        const char* src = (const char*)(Mt + (size_t)b * EE * EE);
#pragma unroll
        for (int i = 0; i < 8; ++i) {
            const int c16 = t + i * 256;          // 0..2047
            const int row = c16 >> 4;
            const int sl  = c16 & 15;
            const int g   = row * 16 + (sl ^ (row & 7));
            gload_lds16(src + g * 16, (char*)Bt + c16 * 16);
        }
    }

    // ---- per-lane A-fragments via sincos (hides the Mt load) ----
    // A layout: row=lane&15, k=(lane>>4)*8+j
    const int grow = n0 + w * 16 + ln15;
    const float* pr = pos + ((size_t)b * NN + grow) * 3;
    const float px = pr[0], py = pr[1], pz = pr[2];
    const float* R = recip + b * 9;
    const float u0 = px * R[0] + py * R[3] + pz * R[6];
    const float u1 = px * R[1] + py * R[4] + pz * R[7];
    const float u2 = px * R[2] + py * R[5] + pz * R[8];

    half8 afrag[4];
#pragma unroll
    for (int mq = 0; mq < 2; ++mq) {
        _Float16 cb[8], sb[8];
#pragma unroll
        for (int jj = 0; jj < 8; ++jj) {
            const int k = mq * 32 + kg * 8 + jj;
            const float ph = 6.28318530717958647692f *
                (u0 * abcL[k * 3 + 0] + u1 * abcL[k * 3 + 1] + u2 * abcL[k * 3 + 2]);
            float s, c;
            __sincosf(ph, &s, &c);
            cb[jj] = (_Float16)c;
            sb[jj] = (_Float16)s;
        }
        afrag[mq]     = *(half8*)cb;   // cos -> k-chunks 0,1
        afrag[mq + 2] = *(half8*)sb;   // sin -> k-chunks 2,3
    }
    __syncthreads();   // drains vmcnt(0): Bt(Mt) ready

    // ---- matmul1: x_pre = A @ M (B-frags from swizzled LDS) ----
    f32x4 acc[8];
#pragma unroll
    for (int nt = 0; nt < 8; ++nt) {
        const int n = nt * 16 + ln15;
        f32x4 a = {0.f, 0.f, 0.f, 0.f};
#pragma unroll
        for (int kc = 0; kc < 4; ++kc) {
            const half8 bf = *(const half8*)&Bt[swz(n, kc * 32 + kg * 8)];
            a = __builtin_amdgcn_mfma_f32_16x16x32_f16(afrag[kc], bf, a, 0, 0, 0);
        }
        acc[nt] = a;
    }

    // ---- bias + silu -> X (f16, swizzled; D layout row=(lane>>4)*4+r2, col=lane&15) ----
#pragma unroll
    for (int nt = 0; nt < 8; ++nt) {
        const int col = nt * 16 + ln15;
        const float bbv = bball[b * EE + col];
#pragma unroll
        for (int r2 = 0; r2 < 4; ++r2) {
            const float v = acc[nt][r2] + bbv;
            const int rr = w * 16 + kg * 4 + r2;
            X[swz(rr, col)] = (_Float16)(v / (1.f + __expf(-v)));
        }
    }
    __syncthreads();   // X visible; all waves done reading Bt(Mt)

    // ---- issue async W2 staging into Bt (same swizzle mapping) ----
    {
        const char* src = (const char*)W2h;
#pragma unroll
        for (int i = 0; i < 8; ++i) {
            const int c16 = t + i * 256;
            const int row = c16 >> 4;
            const int sl  = c16 & 15;
            const int g   = row * 16 + (sl ^ (row & 7));
            gload_lds16(src + g * 16, (char*)Bt + c16 * 16);
        }
    }

    // ---- A-frags for matmul2 from X (hides part of W2 load) ----
    const int arow = w * 16 + ln15;
    half8 a2[4];
#pragma unroll
    for (int kc = 0; kc < 4; ++kc)
        a2[kc] = *(const half8*)&X[swz(arow, kc * 32 + kg * 8)];
    __syncthreads();   // drains vmcnt(0): Bt(W2) ready

    // ---- matmul2: y = X @ W2^T ----
    f32x4 acc2[8];
#pragma unroll
    for (int nt = 0; nt < 8; ++nt) {
        const int n = nt * 16 + ln15;
        f32x4 a = {0.f, 0.f, 0.f, 0.f};
#pragma unroll
        for (int kc = 0; kc < 4; ++kc) {
            const half8 bf = *(const half8*)&Bt[swz(n, kc * 32 + kg * 8)];
            a = __builtin_amdgcn_mfma_f32_16x16x32_f16(a2[kc], bf, a, 0, 0, 0);
        }
        acc2[nt] = a;
    }

    // ---- + b2, LayerNorm over E (16-lane shfl), write out ----
    float y[8][4];
    float s[4] = {0.f, 0.f, 0.f, 0.f}, q[4] = {0.f, 0.f, 0.f, 0.f};
#pragma unroll
    for (int nt = 0; nt < 8; ++nt) {
        const int col = nt * 16 + ln15;
        const float b2v = b2[col];
#pragma unroll
        for (int r2 = 0; r2 < 4; ++r2) {
            const float v = acc2[nt][r2] + b2v;
            y[nt][r2] = v;
            s[r2] += v;
            q[r2] += v * v;
        }
    }
#pragma unroll
    for (int m = 1; m < 16; m <<= 1) {
#pragma unroll
        for (int r2 = 0; r2 < 4; ++r2) {
            s[r2] += __shfl_xor(s[r2], m);
            q[r2] += __shfl_xor(q[r2], m);
        }
    }
    const float inv = 1.f / EE;
    float mu[4], rs[4];
#pragma unroll
    for (int r2 = 0; r2 < 4; ++r2) {
        mu[r2] = s[r2] * inv;
        rs[r2] = rsqrtf(fmaxf(q[r2] * inv - mu[r2] * mu[r2], 0.f) + 1e-5f);
    }
#pragma unroll
    for (int nt = 0; nt < 8; ++nt) {
        const int col = nt * 16 + ln15;
        const float g  = gamma[col];
        const float be = beta[col];
#pragma unroll
        for (int r2 = 0; r2 < 4; ++r2) {
            const int rr = w * 16 + kg * 4 + r2;
            out[((size_t)b * NN + n0 + rr) * EE + col] = (y[nt][r2] - mu[r2]) * rs[r2] * g + be;
        }
    }
}

extern "C" void kernel_launch(void* const* d_in, const int* in_sizes, int n_in,
                              void* d_out, int out_size, void* d_ws, size_t ws_size,
                              hipStream_t stream) {
    const float* pos    = (const float*)d_in[0];
    const float* recip  = (const float*)d_in[1];
    const int*   sgp    = (const int*)d_in[2];
    const float* abc    = (const float*)d_in[3];
    const float* graphs = (const float*)d_in[4];
    const float* wr     = (const float*)d_in[5];
    const float* wi     = (const float*)d_in[6];
    const float* br     = (const float*)d_in[7];
    const float* bi     = (const float*)d_in[8];
    const float* W2     = (const float*)d_in[9];
    const float* b2     = (const float*)d_in[10];
    const float* gm     = (const float*)d_in[11];
    const float* bt     = (const float*)d_in[12];
    float* out = (float*)d_out;

    char* ws = (char*)d_ws;
    _Float16* Mt    = (_Float16*)ws;                                    // B*E*E f16 = 8 MiB
    _Float16* W2h   = (_Float16*)(ws + (size_t)BB * EE * EE * 2);       // E*E f16 = 32 KiB
    float*    bball = (float*)(ws + (size_t)BB * EE * EE * 2 + 32768);  // B*E f32

    hipLaunchKernelGGL(prep_kernel, dim3(BB), dim3(256), 0, stream,
                       recip, sgp, graphs, wr, wi, br, bi, W2, Mt, bball, W2h);
    hipLaunchKernelGGL(main_kernel, dim3(BB * NN / TM), dim3(256), 0, stream,
                       pos, recip, abc, Mt, bball, W2h, b2, gm, bt, out);
}